// Round 1
// baseline (4301.140 us; speedup 1.0000x reference)
//
#include <hip/hip_runtime.h>
#include <hip/hip_bf16.h>

// Problem: attention-augmented LSTM encoder.
// B=2048, T=128, N=128, H=256.
// Key algebraic simplification: softmax(s[b] + precomp[b,:] + bias) over n
// == softmax(precomp[b,:])  (shift invariance) -> attention weights are
// time-invariant and independent of h/c. w_h, w_c, b_attn are dead.
//
// Kernel 1: attn = softmax_n(sum_t x[b,t,n]*w_x[t]); out0[b,t,n] = attn*x.
// Kernel 2 (cooperative, 256 blocks = 1/CU): LSTM recurrence.
//   Grid decomposition: 32 rowgroups (64 batch rows) x 8 colgroups (32 h-cols
//   -> 128 gate cols). Weights for a block's gate columns live in VGPRs as
//   persistent MFMA B-fragments (no per-step weight traffic). h is exchanged
//   via a ping-pong bf16 buffer in d_ws with per-rowgroup release/acquire
//   flag sync. Rowgroup's 8 blocks co-located on one XCD via bid%8 swizzle.

#define B_ 2048
#define T_ 128
#define N_ 128
#define H_ 256

typedef float f32x4 __attribute__((ext_vector_type(4)));
typedef short bf16x8 __attribute__((ext_vector_type(8)));
typedef unsigned short u16;
typedef u16 u16x4 __attribute__((ext_vector_type(4)));
typedef u16 u16x8 __attribute__((ext_vector_type(8)));

__device__ __forceinline__ u16 f2bf(float f) {
  unsigned int u = __float_as_uint(f);
  u += 0x7fffu + ((u >> 16) & 1u);   // round-to-nearest-even
  return (u16)(u >> 16);
}
__device__ __forceinline__ float sigm(float x) { return 1.f / (1.f + __expf(-x)); }
__device__ __forceinline__ float tanh_(float x) {
  float e = __expf(2.f * x);
  return 1.f - 2.f / (e + 1.f);
}

// ---------------------------------------------------------------- kernel 1
__global__ __launch_bounds__(128) void attn_wx_kernel(
    const float* __restrict__ x, const float* __restrict__ w_attn,
    float* __restrict__ out0) {
  const int b = blockIdx.x;
  const int n = threadIdx.x;             // 0..127
  const float* xb = x + (size_t)b * (T_ * N_);
  __shared__ float red[N_];
  float xv[T_];
  float p = 0.f;
#pragma unroll
  for (int t = 0; t < T_; ++t) {
    xv[t] = xb[t * N_ + n];              // coalesced across n
    p += xv[t] * w_attn[2 * H_ + t];     // scalar (uniform) load
  }
  red[n] = p;
  __syncthreads();
  float m = red[0];
  for (int i = 1; i < N_; ++i) m = fmaxf(m, red[i]);
  float e = __expf(p - m);
  __syncthreads();
  red[n] = e;
  __syncthreads();
  float s = 0.f;
  for (int i = 0; i < N_; ++i) s += red[i];
  const float a = e / s;
  float* ob = out0 + (size_t)b * (T_ * N_);
#pragma unroll
  for (int t = 0; t < T_; ++t) ob[t * N_ + n] = a * xv[t];
}

// ---------------------------------------------------------------- kernel 2
struct SharedU {
  union {
    struct {
      u16 wx[64][136];   // 64 rows x 128 bf16 (+8 pad)   A-operand k in [0,128)
      u16 h[64][264];    // 64 rows x 256 bf16 (+8 pad)   A-operand k in [128,384)
    } s;
    float gates[128][68];  // transposed gate tile [gatecol][row] (+4 pad)
  };
};

__global__ __launch_bounds__(256) void lstm_kernel(
    const float* __restrict__ wx_src,   // = out0 (f32 weighted inputs)
    const float* __restrict__ w_ih,     // [4H][N]
    const float* __restrict__ w_hh,     // [4H][H]
    const float* __restrict__ b_ih, const float* __restrict__ b_hh,
    float* __restrict__ out1,           // [B][T][H]
    u16* __restrict__ hbuf,             // [2][B][H] bf16 ping-pong
    int* __restrict__ flags) {          // [32][T]
  __shared__ SharedU u;
  const int bid = blockIdx.x;
  // XCD co-location: rowgroup r's 8 blocks share bid%8 (one XCD).
  const int r  = (bid & 7) + ((bid >> 6) << 3);   // 0..31
  const int cg = (bid >> 3) & 7;                  // 0..7
  const int rb = r * 64;
  const int tid  = threadIdx.x;
  const int wave = tid >> 6;      // 0..3  == gate index (i,f,g,o)
  const int lane = tid & 63;
  const int l15  = lane & 15;
  const int koff = (lane >> 4) * 8;

  // --- persistent B fragments: wave `wave` owns gate `wave`, cols cg*32..+32
  bf16x8 bfrag[2][12];
#pragma unroll
  for (int nt = 0; nt < 2; ++nt) {
    const int grow = wave * H_ + cg * 32 + nt * 16 + l15;  // row of w_ih/w_hh
#pragma unroll
    for (int kc = 0; kc < 12; ++kc) {
      bf16x8 v;
#pragma unroll
      for (int j = 0; j < 8; ++j) {
        const int k = kc * 32 + koff + j;
        const float w = (k < N_) ? w_ih[(size_t)grow * N_ + k]
                                 : w_hh[(size_t)grow * H_ + (k - N_)];
        v[j] = (short)f2bf(w);
      }
      bfrag[nt][kc] = v;
    }
  }

  // --- cell ownership: thread -> (rows rowb..rowb+7, h-col hc)
  const int hc   = tid & 31;
  const int rowb = (tid >> 5) * 8;
  float bias[4];
#pragma unroll
  for (int g = 0; g < 4; ++g) {
    const int grow = g * H_ + cg * 32 + hc;
    bias[g] = b_ih[grow] + b_hh[grow];
  }
  float creg[8];
#pragma unroll
  for (int i = 0; i < 8; ++i) creg[i] = 0.f;

  const int srow = tid >> 2, sseg = tid & 3;  // staging map: 4 thr/row

  for (int t = 0; t < T_; ++t) {
    if (t > 0 && tid == 0) {
      while (__hip_atomic_load(&flags[r * T_ + t - 1], __ATOMIC_ACQUIRE,
                               __HIP_MEMORY_SCOPE_AGENT) < 8)
        __builtin_amdgcn_s_sleep(1);
    }
    __syncthreads();  // prev cell phase done (LDS free) + h ready

    // --- stage wx (f32 -> bf16) and h (bf16) into LDS
    {
      const float* src = wx_src + (size_t)(rb + srow) * (T_ * N_) + t * N_ + sseg * 32;
#pragma unroll
      for (int v = 0; v < 8; ++v) {
        f32x4 d = *(const f32x4*)(src + v * 4);
        u16x4 w;
        w[0] = f2bf(d[0]); w[1] = f2bf(d[1]); w[2] = f2bf(d[2]); w[3] = f2bf(d[3]);
        *(u16x4*)&u.s.wx[srow][sseg * 32 + v * 4] = w;
      }
      if (t > 0) {
        const u16* hs = hbuf + ((size_t)(t & 1)) * B_ * H_ + (size_t)(rb + srow) * H_ + sseg * 64;
#pragma unroll
        for (int v = 0; v < 8; ++v)
          *(u16x8*)&u.s.h[srow][sseg * 64 + v * 8] = *(const u16x8*)(hs + v * 8);
      }
    }
    __syncthreads();

    // --- MFMA: gates[64 x 128] = [wx | h] @ Wt   (K = 384, K=128 at t==0)
    f32x4 acc[4][2] = {};
#pragma unroll
    for (int mt = 0; mt < 4; ++mt) {
      const int arow = mt * 16 + l15;
#pragma unroll
      for (int kc = 0; kc < 4; ++kc) {
        bf16x8 a = *(const bf16x8*)&u.s.wx[arow][kc * 32 + koff];
        acc[mt][0] = __builtin_amdgcn_mfma_f32_16x16x32_bf16(a, bfrag[0][kc], acc[mt][0], 0, 0, 0);
        acc[mt][1] = __builtin_amdgcn_mfma_f32_16x16x32_bf16(a, bfrag[1][kc], acc[mt][1], 0, 0, 0);
      }
      if (t > 0) {
#pragma unroll
        for (int kc = 4; kc < 12; ++kc) {
          bf16x8 a = *(const bf16x8*)&u.s.h[arow][(kc - 4) * 32 + koff];
          acc[mt][0] = __builtin_amdgcn_mfma_f32_16x16x32_bf16(a, bfrag[0][kc], acc[mt][0], 0, 0, 0);
          acc[mt][1] = __builtin_amdgcn_mfma_f32_16x16x32_bf16(a, bfrag[1][kc], acc[mt][1], 0, 0, 0);
        }
      }
    }
    __syncthreads();  // all MFMA LDS reads done before aliasing write

    // --- gates -> LDS, transposed [gatecol][row] so cell update is per-lane
#pragma unroll
    for (int mt = 0; mt < 4; ++mt)
#pragma unroll
      for (int nt = 0; nt < 2; ++nt) {
        const int q = wave * 32 + nt * 16 + l15;          // local gate col
        const int rbase = mt * 16 + (lane >> 4) * 4;      // C/D row mapping
        *(f32x4*)&u.gates[q][rbase] = acc[mt][nt];
      }
    __syncthreads();

    // --- LSTM cell
    u16* hb_next = hbuf + ((size_t)((t + 1) & 1)) * B_ * H_;
#pragma unroll
    for (int rr = 0; rr < 8; ++rr) {
      const int row = rowb + rr;
      const float gi = u.gates[hc][row]      + bias[0];
      const float gf = u.gates[32 + hc][row] + bias[1];
      const float gg = u.gates[64 + hc][row] + bias[2];
      const float go = u.gates[96 + hc][row] + bias[3];
      const float c = sigm(gf) * creg[rr] + sigm(gi) * tanh_(gg);
      creg[rr] = c;
      const float h = sigm(go) * tanh_(c);
      out1[(size_t)(rb + row) * (T_ * H_) + t * H_ + cg * 32 + hc] = h;
      hb_next[(size_t)(rb + row) * H_ + cg * 32 + hc] = f2bf(h);
    }
    __threadfence();
    __syncthreads();
    if (tid == 0)
      __hip_atomic_fetch_add(&flags[r * T_ + t], 1, __ATOMIC_RELEASE,
                             __HIP_MEMORY_SCOPE_AGENT);
  }
}

// ---------------------------------------------------------------- launch
extern "C" void kernel_launch(void* const* d_in, const int* in_sizes, int n_in,
                              void* d_out, int out_size, void* d_ws, size_t ws_size,
                              hipStream_t stream) {
  const float* x      = (const float*)d_in[0];
  const float* w_ih   = (const float*)d_in[1];
  const float* w_hh   = (const float*)d_in[2];
  const float* b_ih   = (const float*)d_in[3];
  const float* b_hh   = (const float*)d_in[4];
  const float* w_attn = (const float*)d_in[5];
  // d_in[6] (b_attn) is provably unused (softmax shift invariance).

  float* out0 = (float*)d_out;                       // [B][T][N] input_weighted
  float* out1 = out0 + (size_t)B_ * T_ * N_;         // [B][T][H] input_encoded
  int* flags  = (int*)d_ws;                          // [32][T]
  u16* hbuf   = (u16*)((char*)d_ws + 65536);         // [2][B][H] bf16

  hipMemsetAsync(d_ws, 0, 32 * T_ * sizeof(int), stream);
  attn_wx_kernel<<<dim3(B_), dim3(N_), 0, stream>>>(x, w_attn, out0);

  const float* wx_src = out0;
  void* args[] = {(void*)&wx_src, (void*)&w_ih, (void*)&w_hh, (void*)&b_ih,
                  (void*)&b_hh,  (void*)&out1, (void*)&hbuf, (void*)&flags};
  hipLaunchCooperativeKernel((void*)lstm_kernel, dim3(256), dim3(256), args, 0, stream);
}

// Round 2
// 3554.008 us; speedup vs baseline: 1.2102x; 1.2102x over previous
//
#include <hip/hip_runtime.h>
#include <hip/hip_bf16.h>

// Attention-augmented LSTM encoder. B=2048, T=128, N=128, H=256.
// softmax(s[b]+precomp+bias) over n == softmax(precomp) (shift invariance)
// -> attention is time-invariant; w_h, w_c, b_attn dead.
//
// Round-2 redesign: NO inter-block communication (round-1 agent-scope
// acquire/release fences invalidated the XCD L2 every poll -> 33us/step).
// Each block owns M=32 batch rows, computes all 4H=1024 gate cols, keeps
// h in double-buffered LDS (one barrier/step), c in regs, and re-streams
// the 768 KB bf16 pre-packed weight matrix from L2 every step.
// Lane owns the same h-column in all 4 gate quadrants -> cell update is
// pure per-lane register math (no gate redistribution).

#define B_ 2048
#define T_ 128
#define N_ 128
#define H_ 256
#define M_ 32
#define NBLK (B_ / M_)   // 64 blocks

typedef float f32x4 __attribute__((ext_vector_type(4)));
typedef short bf16x8 __attribute__((ext_vector_type(8)));
typedef unsigned short u16;

__device__ __forceinline__ u16 f2bf(float f) {
  unsigned int u = __float_as_uint(f);
  u += 0x7fffu + ((u >> 16) & 1u);   // round-to-nearest-even
  return (u16)(u >> 16);
}
__device__ __forceinline__ float sigm(float x) { return 1.f / (1.f + __expf(-x)); }
__device__ __forceinline__ float tanh_(float x) {
  float e = __expf(2.f * x);
  return 1.f - 2.f / (e + 1.f);
}

// ---------------------------------------------------------------- kernel 1
__global__ __launch_bounds__(128) void attn_wx_kernel(
    const float* __restrict__ x, const float* __restrict__ w_attn,
    float* __restrict__ out0) {
  const int b = blockIdx.x;
  const int n = threadIdx.x;             // 0..127
  const float* xb = x + (size_t)b * (T_ * N_);
  __shared__ float red[N_];
  float xv[T_];
  float p = 0.f;
#pragma unroll
  for (int t = 0; t < T_; ++t) {
    xv[t] = xb[t * N_ + n];              // coalesced across n
    p += xv[t] * w_attn[2 * H_ + t];     // uniform load
  }
  red[n] = p;
  __syncthreads();
  float m = red[0];
  for (int i = 1; i < N_; ++i) m = fmaxf(m, red[i]);
  float e = __expf(p - m);
  __syncthreads();
  red[n] = e;
  __syncthreads();
  float s = 0.f;
  for (int i = 0; i < N_; ++i) s += red[i];
  const float a = e / s;
  float* ob = out0 + (size_t)b * (T_ * N_);
#pragma unroll
  for (int t = 0; t < T_; ++t) ob[t * N_ + n] = a * xv[t];
}

// ------------------------------------------------------- weight prepack
// wpk layout: frag(w=0..15, q=0..3, kc=0..11) at ((w*4+q)*12+kc)*512,
// 64 lanes x 8 bf16: element j of lane l = W[q*256+w*16+(l&15)][kc*32+((l>>4)<<3)+j]
// where W = [w_ih | w_hh] (K = 128 + 256 = 384).
__global__ __launch_bounds__(256) void prepack_kernel(
    const float* __restrict__ w_ih, const float* __restrict__ w_hh,
    u16* __restrict__ wpk) {
  const int idx = blockIdx.x * 256 + threadIdx.x;  // 393216 total
  const int j = idx & 7;
  const int l = (idx >> 3) & 63;
  const int rest = idx >> 9;        // (w*4+q)*12 + kc, 0..767
  const int kc = rest % 12;
  const int wq = rest / 12;
  const int q = wq & 3;
  const int w = wq >> 2;
  const int grow = q * H_ + w * 16 + (l & 15);
  const int k = kc * 32 + ((l >> 4) << 3) + j;
  const float v = (k < N_) ? w_ih[(size_t)grow * N_ + k]
                           : w_hh[(size_t)grow * H_ + (k - N_)];
  wpk[idx] = f2bf(v);
}

// ---------------------------------------------------------------- kernel 2
__global__ __launch_bounds__(1024) void lstm_kernel(
    const float* __restrict__ wx,     // out0, f32 [B][T][N]
    const u16* __restrict__ wpk,      // packed bf16 weights (768 KB)
    const float* __restrict__ b_ih, const float* __restrict__ b_hh,
    float* __restrict__ out1) {       // f32 [B][T][H]
  __shared__ u16 hsh[2][M_][264];     // h double buffer, pad 8 u16 (2-way max)
  const int tid  = threadIdx.x;
  const int w    = tid >> 6;          // wave 0..15 -> h-col group
  const int lane = tid & 63;
  const int l15  = lane & 15;
  const int koff = (lane >> 4) << 3;
  const int rb   = blockIdx.x * M_;
  const int hcol = w * 16 + l15;

  float bias[4];
#pragma unroll
  for (int q = 0; q < 4; ++q)
    bias[q] = b_ih[q * H_ + hcol] + b_hh[q * H_ + hcol];

  // zero h buffer 0 (read at t=0)
  {
    u16* hz = &hsh[0][0][0];
    for (int i = tid; i < M_ * 264; i += 1024) hz[i] = 0;
  }
  __syncthreads();

  float creg[2][4] = {};
  const u16* wpw = wpk + ((size_t)w * 4 * 12) * 512 + (size_t)lane * 8;
  int cur = 0;

  for (int t = 0; t < T_; ++t) {
    f32x4 acc[2][4] = {};

    // ---- K part 1: wx (k 0..127), A from global f32 -> bf16
#pragma unroll
    for (int kc = 0; kc < 4; ++kc) {
      bf16x8 a[2];
#pragma unroll
      for (int mt = 0; mt < 2; ++mt) {
        const float* p = wx + (size_t)(rb + mt * 16 + l15) * (T_ * N_)
                            + t * N_ + kc * 32 + koff;
        f32x4 x0 = *(const f32x4*)p;
        f32x4 x1 = *(const f32x4*)(p + 4);
        bf16x8 av;
        av[0] = (short)f2bf(x0[0]); av[1] = (short)f2bf(x0[1]);
        av[2] = (short)f2bf(x0[2]); av[3] = (short)f2bf(x0[3]);
        av[4] = (short)f2bf(x1[0]); av[5] = (short)f2bf(x1[1]);
        av[6] = (short)f2bf(x1[2]); av[7] = (short)f2bf(x1[3]);
        a[mt] = av;
      }
#pragma unroll
      for (int q = 0; q < 4; ++q) {
        bf16x8 bv = *(const bf16x8*)(wpw + (size_t)(q * 12 + kc) * 512);
        acc[0][q] = __builtin_amdgcn_mfma_f32_16x16x32_bf16(a[0], bv, acc[0][q], 0, 0, 0);
        acc[1][q] = __builtin_amdgcn_mfma_f32_16x16x32_bf16(a[1], bv, acc[1][q], 0, 0, 0);
      }
    }

    // ---- K part 2: h (k 128..383), A from LDS
#pragma unroll
    for (int kc = 4; kc < 12; ++kc) {
      bf16x8 a[2];
#pragma unroll
      for (int mt = 0; mt < 2; ++mt)
        a[mt] = *(const bf16x8*)&hsh[cur][mt * 16 + l15][(kc - 4) * 32 + koff];
#pragma unroll
      for (int q = 0; q < 4; ++q) {
        bf16x8 bv = *(const bf16x8*)(wpw + (size_t)(q * 12 + kc) * 512);
        acc[0][q] = __builtin_amdgcn_mfma_f32_16x16x32_bf16(a[0], bv, acc[0][q], 0, 0, 0);
        acc[1][q] = __builtin_amdgcn_mfma_f32_16x16x32_bf16(a[1], bv, acc[1][q], 0, 0, 0);
      }
    }

    // ---- LSTM cell: fully in-register (lane owns hcol in all 4 quadrants)
    const int nxt = cur ^ 1;
#pragma unroll
    for (int mt = 0; mt < 2; ++mt)
#pragma unroll
      for (int r = 0; r < 4; ++r) {
        const float gi = acc[mt][0][r] + bias[0];
        const float gf = acc[mt][1][r] + bias[1];
        const float gg = acc[mt][2][r] + bias[2];
        const float go = acc[mt][3][r] + bias[3];
        const float c = sigm(gf) * creg[mt][r] + sigm(gi) * tanh_(gg);
        creg[mt][r] = c;
        const float h = sigm(go) * tanh_(c);
        const int row = mt * 16 + ((lane >> 4) << 2) + r;
        out1[(size_t)(rb + row) * (T_ * H_) + (size_t)t * H_ + hcol] = h;
        hsh[nxt][row][hcol] = f2bf(h);
      }
    __syncthreads();   // h[nxt] complete before next step reads it
    cur = nxt;
  }
}

// ---------------------------------------------------------------- launch
extern "C" void kernel_launch(void* const* d_in, const int* in_sizes, int n_in,
                              void* d_out, int out_size, void* d_ws, size_t ws_size,
                              hipStream_t stream) {
  const float* x      = (const float*)d_in[0];
  const float* w_ih   = (const float*)d_in[1];
  const float* w_hh   = (const float*)d_in[2];
  const float* b_ih   = (const float*)d_in[3];
  const float* b_hh   = (const float*)d_in[4];
  const float* w_attn = (const float*)d_in[5];
  // d_in[6] (b_attn) provably unused (softmax shift invariance).

  float* out0 = (float*)d_out;                   // [B][T][N] input_weighted
  float* out1 = out0 + (size_t)B_ * T_ * N_;     // [B][T][H] input_encoded
  u16* wpk    = (u16*)d_ws;                      // 768 KB packed weights

  prepack_kernel<<<dim3(1536), dim3(256), 0, stream>>>(w_ih, w_hh, wpk);
  attn_wx_kernel<<<dim3(B_), dim3(N_), 0, stream>>>(x, w_attn, out0);
  lstm_kernel<<<dim3(NBLK), dim3(1024), 0, stream>>>(out0, wpk, b_ih, b_hh, out1);
}

// Round 3
// 1215.466 us; speedup vs baseline: 3.5387x; 2.9240x over previous
//
#include <hip/hip_runtime.h>
#include <hip/hip_bf16.h>

// Attention-augmented LSTM encoder. B=2048, T=128, N=128, H=256.
// softmax shift-invariance -> attention time-invariant; w_h/w_c/b_attn dead.
//
// Round 3: weight-stationary. 256 blocks (32 rowgroups x 8 colgroups), each
// wave keeps its 48 MFMA B-fragments in VGPRs (192 regs). h is exchanged
// through the device coherence point (L3) with RELAXED atomics + sc0sc1
// loads/stores -- no acquire/release, so no buffer_inv/buffer_wbl2 L2 nukes
// (round-1 failure) and no per-step 768KB weight restream (round-2 failure).

#define B_ 2048
#define T_ 128
#define N_ 128
#define H_ 256

typedef float f32x4 __attribute__((ext_vector_type(4)));
typedef short bf16x8 __attribute__((ext_vector_type(8)));
typedef unsigned short u16;

__device__ __forceinline__ u16 f2bf(float f) {
  unsigned int u = __float_as_uint(f);
  u += 0x7fffu + ((u >> 16) & 1u);   // RNE
  return (u16)(u >> 16);
}
__device__ __forceinline__ float sigm(float x) { return 1.f / (1.f + __expf(-x)); }
__device__ __forceinline__ float tanh_(float x) {
  float e = __expf(2.f * x);
  return 1.f - 2.f / (e + 1.f);
}

// device-coherent (bypass L1+L2) 16B load / 2B store: relaxed, no cache ops
__device__ __forceinline__ bf16x8 ld16_dev(const u16* p) {
  bf16x8 v;
  asm volatile("global_load_dwordx4 %0, %1, off sc0 sc1" : "=v"(v) : "v"(p));
  return v;
}
__device__ __forceinline__ void st2_dev(u16* p, unsigned int v) {
  asm volatile("global_store_short %0, %1, off sc0 sc1" :: "v"(p), "v"(v));
}

// ---------------------------------------------------------------- kernel 1
__global__ __launch_bounds__(128) void attn_wx_kernel(
    const float* __restrict__ x, const float* __restrict__ w_attn,
    float* __restrict__ out0) {
  const int b = blockIdx.x;
  const int n = threadIdx.x;
  const float* xb = x + (size_t)b * (T_ * N_);
  __shared__ float red[N_];
  float xv[T_];
  float p = 0.f;
#pragma unroll
  for (int t = 0; t < T_; ++t) {
    xv[t] = xb[t * N_ + n];
    p += xv[t] * w_attn[2 * H_ + t];
  }
  red[n] = p;
  __syncthreads();
  float m = red[0];
  for (int i = 1; i < N_; ++i) m = fmaxf(m, red[i]);
  float e = __expf(p - m);
  __syncthreads();
  red[n] = e;
  __syncthreads();
  float s = 0.f;
  for (int i = 0; i < N_; ++i) s += red[i];
  const float a = e / s;
  float* ob = out0 + (size_t)b * (T_ * N_);
#pragma unroll
  for (int t = 0; t < T_; ++t) ob[t * N_ + n] = a * xv[t];
}

// ------------------------------------------------------- weight prepack
// frag(g16=0..15, q=0..3, kc=0..11) at ((g16*4+q)*12+kc)*512; elem j of lane l
// = W[q*256+g16*16+(l&15)][kc*32+((l>>4)<<3)+j], W = [w_ih | w_hh], K=384.
__global__ __launch_bounds__(256) void prepack_kernel(
    const float* __restrict__ w_ih, const float* __restrict__ w_hh,
    u16* __restrict__ wpk) {
  const int idx = blockIdx.x * 256 + threadIdx.x;  // 393216
  const int j = idx & 7;
  const int l = (idx >> 3) & 63;
  const int rest = idx >> 9;
  const int kc = rest % 12;
  const int wq = rest / 12;
  const int q = wq & 3;
  const int g16 = wq >> 2;
  const int grow = q * H_ + g16 * 16 + (l & 15);
  const int k = kc * 32 + ((l >> 4) << 3) + j;
  const float v = (k < N_) ? w_ih[(size_t)grow * N_ + k]
                           : w_hh[(size_t)grow * H_ + (k - N_)];
  wpk[idx] = f2bf(v);
}

// ---------------------------------------------------------------- kernel 2
__global__ __launch_bounds__(256, 1) void lstm_kernel(
    const float* __restrict__ wx,      // out0 f32 [B][T][N]
    const u16* __restrict__ wpk,
    const float* __restrict__ b_ih, const float* __restrict__ b_hh,
    float* __restrict__ out1,          // f32 [B][T][H]
    u16* __restrict__ hbuf,            // [2][B][H] bf16 ping-pong (L3-coherent)
    int* __restrict__ flags) {         // [32][T]
  const int bid = blockIdx.x;
  const int r   = (bid & 7) * 4 + (bid >> 6);   // rowgroup 0..31 (XCD-grouped)
  const int cg  = (bid >> 3) & 7;               // colgroup 0..7
  const int rb  = r * 64;
  const int tid = threadIdx.x;
  const int wv  = tid >> 6;
  const int rh  = wv >> 1;                      // rowhalf 0..1 (32 rows)
  const int g16 = cg * 2 + (wv & 1);            // 16-col group 0..15
  const int lane = tid & 63;
  const int l15  = lane & 15;
  const int koff = (lane >> 4) << 3;
  const int hcol = g16 * 16 + l15;
  const int rowbase = rb + rh * 32;

  // persistent weights: 48 frags = 192 VGPRs
  bf16x8 wfrag[4][12];
  {
    const u16* wp = wpk + ((size_t)(g16 * 4) * 12) * 512 + (size_t)lane * 8;
#pragma unroll
    for (int q = 0; q < 4; ++q)
#pragma unroll
      for (int kc = 0; kc < 12; ++kc)
        wfrag[q][kc] = *(const bf16x8*)(wp + (size_t)(q * 12 + kc) * 512);
  }
  float bias[4];
#pragma unroll
  for (int q = 0; q < 4; ++q)
    bias[q] = b_ih[q * H_ + hcol] + b_hh[q * H_ + hcol];
  float creg[2][4] = {};

  for (int t = 0; t < T_; ++t) {
    f32x4 acc[2][4] = {};

    // ---- K part 1: wx (k 0..127), overlaps producers' previous step
#pragma unroll
    for (int kc = 0; kc < 4; ++kc) {
      bf16x8 a[2];
#pragma unroll
      for (int mt = 0; mt < 2; ++mt) {
        const float* p = wx + (size_t)(rowbase + mt * 16 + l15) * (T_ * N_)
                            + (size_t)t * N_ + kc * 32 + koff;
        f32x4 x0 = *(const f32x4*)p;
        f32x4 x1 = *(const f32x4*)(p + 4);
        bf16x8 av;
        av[0] = (short)f2bf(x0[0]); av[1] = (short)f2bf(x0[1]);
        av[2] = (short)f2bf(x0[2]); av[3] = (short)f2bf(x0[3]);
        av[4] = (short)f2bf(x1[0]); av[5] = (short)f2bf(x1[1]);
        av[6] = (short)f2bf(x1[2]); av[7] = (short)f2bf(x1[3]);
        a[mt] = av;
      }
#pragma unroll
      for (int q = 0; q < 4; ++q) {
        acc[0][q] = __builtin_amdgcn_mfma_f32_16x16x32_bf16(a[0], wfrag[q][kc], acc[0][q], 0, 0, 0);
        acc[1][q] = __builtin_amdgcn_mfma_f32_16x16x32_bf16(a[1], wfrag[q][kc], acc[1][q], 0, 0, 0);
      }
    }

    // ---- K part 2: h (k 128..383), gathered straight from L3
    if (t > 0) {
      if (tid == 0) {
        while (__hip_atomic_load(&flags[r * T_ + t - 1], __ATOMIC_RELAXED,
                                 __HIP_MEMORY_SCOPE_AGENT) < 8)
          __builtin_amdgcn_s_sleep(2);
      }
      __syncthreads();
      const u16* hb = hbuf + (size_t)((t - 1) & 1) * B_ * H_;
      bf16x8 ah[2][8];
#pragma unroll
      for (int mt = 0; mt < 2; ++mt)
#pragma unroll
        for (int kc = 0; kc < 8; ++kc)
          ah[mt][kc] = ld16_dev(hb + (size_t)(rowbase + mt * 16 + l15) * H_ + kc * 32 + koff);
      asm volatile("s_waitcnt vmcnt(0)" ::: "memory");
      __builtin_amdgcn_sched_barrier(0);
#pragma unroll
      for (int kc = 0; kc < 8; ++kc)
#pragma unroll
        for (int q = 0; q < 4; ++q) {
          acc[0][q] = __builtin_amdgcn_mfma_f32_16x16x32_bf16(ah[0][kc], wfrag[q][4 + kc], acc[0][q], 0, 0, 0);
          acc[1][q] = __builtin_amdgcn_mfma_f32_16x16x32_bf16(ah[1][kc], wfrag[q][4 + kc], acc[1][q], 0, 0, 0);
        }
    }

    // ---- LSTM cell (fully in-register) + stores
    u16* hb_n = hbuf + (size_t)(t & 1) * B_ * H_;
#pragma unroll
    for (int mt = 0; mt < 2; ++mt)
#pragma unroll
      for (int rr = 0; rr < 4; ++rr) {
        const float gi = acc[mt][0][rr] + bias[0];
        const float gf = acc[mt][1][rr] + bias[1];
        const float gg = acc[mt][2][rr] + bias[2];
        const float go = acc[mt][3][rr] + bias[3];
        const float c = sigm(gf) * creg[mt][rr] + sigm(gi) * tanh_(gg);
        creg[mt][rr] = c;
        const float h = sigm(go) * tanh_(c);
        const int row = rowbase + mt * 16 + ((lane >> 4) << 2) + rr;
        out1[(size_t)row * (T_ * H_) + (size_t)t * H_ + hcol] = h;
        st2_dev(hb_n + (size_t)row * H_ + hcol, (unsigned int)f2bf(h));
      }
    asm volatile("s_waitcnt vmcnt(0)" ::: "memory");  // h visible at L3
    __syncthreads();                                   // all waves done
    if (tid == 0)
      __hip_atomic_fetch_add(&flags[r * T_ + t], 1, __ATOMIC_RELAXED,
                             __HIP_MEMORY_SCOPE_AGENT);
  }
}

// ---------------------------------------------------------------- launch
extern "C" void kernel_launch(void* const* d_in, const int* in_sizes, int n_in,
                              void* d_out, int out_size, void* d_ws, size_t ws_size,
                              hipStream_t stream) {
  const float* x      = (const float*)d_in[0];
  const float* w_ih   = (const float*)d_in[1];
  const float* w_hh   = (const float*)d_in[2];
  const float* b_ih   = (const float*)d_in[3];
  const float* b_hh   = (const float*)d_in[4];
  const float* w_attn = (const float*)d_in[5];
  // d_in[6] (b_attn) provably unused (softmax shift invariance).

  float* out0 = (float*)d_out;                   // [B][T][N] input_weighted
  float* out1 = out0 + (size_t)B_ * T_ * N_;     // [B][T][H] input_encoded

  int* flags = (int*)d_ws;                                   // 16 KB
  u16* wpk   = (u16*)((char*)d_ws + 16384);                  // 768 KB
  u16* hbuf  = (u16*)((char*)d_ws + 16384 + 786432);         // 2 MB

  hipMemsetAsync(d_ws, 0, 32 * T_ * sizeof(int), stream);
  prepack_kernel<<<dim3(1536), dim3(256), 0, stream>>>(w_ih, w_hh, wpk);
  attn_wx_kernel<<<dim3(B_), dim3(N_), 0, stream>>>(x, w_attn, out0);
  lstm_kernel<<<dim3(256), dim3(256), 0, stream>>>(out0, wpk, b_ih, b_hh,
                                                   out1, hbuf, flags);
}